// Round 2
// baseline (160.916 us; speedup 1.0000x reference)
//
#include <hip/hip_runtime.h>
#include <hip/hip_cooperative_groups.h>

// SDT forward, fp16 MFMA (fp32 accumulate), v3: single cooperative dispatch.
//   Phase A: all 256 blocks stage x-tile (LDS) while blocks 0..67 convert
//            W / value to fp16 frag-major workspace. threadfence + grid.sync.
//   Phase B: v1's proven GEMM structure (32 rows/block, 8 waves, depth-1 B
//            prefetch) + fused sigmoid/bias/reg epilogue on registers
//            (no L_s logit round-trip) + vt prefetched to regs before 2b.
// Layouts (HW-verified): A/B^T lane&15->row, (lane>>4)*8->k;
// C/D: col=lane&15, row=(lane>>4)*4+reg.

typedef __attribute__((ext_vector_type(8))) _Float16 half8;
typedef __attribute__((ext_vector_type(4))) _Float16 half4;
typedef __attribute__((ext_vector_type(4))) float floatx4;

namespace cg = cooperative_groups;

constexpr int O = 64;
constexpr int XSTR = 520;   // x-tile LDS row stride (halfs): 1040 B
constexpr int PSTR = 280;   // P_h row stride (halfs): 560 B (16B-aligned)
constexpr int LSTR = 260;   // L_s row stride (floats)

__global__ __launch_bounds__(512, 2) void sdt_fused(
    const float* __restrict__ x, const float* __restrict__ Ws,
    const float* __restrict__ bs, const float* __restrict__ value,
    _Float16* __restrict__ wt, _Float16* __restrict__ vt,
    float* __restrict__ out, float* __restrict__ reg_out)
{
  // Overlay: phase B1 x-tile fp16 (33280 B) / phase B2 L_s + P_h.
  __shared__ __align__(16) char smem[33280 + 17920];
  _Float16* xh_s = (_Float16*)smem;              // [32][520]
  float*    L_s  = (float*)smem;                 // [32][260]
  _Float16* P_h  = (_Float16*)(smem + 33280);    // [32][280]
  __shared__ float red_s[8];

  const int t = threadIdx.x, lane = t & 63, w = t >> 6;   // 8 waves
  const int q = lane >> 4, r16 = lane & 15;
  const int bid = blockIdx.x;
  const int R0 = bid * 32;

  // ======== phase A: x-tile staging (all blocks) + W/value convert ========
  {
    const int row = t >> 4, l4 = (t & 15) * 4;
    const float* xrow = x + (size_t)(R0 + row) * 512;
#pragma unroll
    for (int i = 0; i < 8; ++i) {
      const int k = l4 + i * 64;
      float4 v = *(const float4*)(xrow + k);
      half4 h = {(_Float16)v.x, (_Float16)v.y, (_Float16)v.z, (_Float16)v.w};
      *(half4*)&xh_s[row * XSTR + k] = h;
    }
  }
  if (bid < 64) {                      // W: 8 k-rows per block, coalesced
    if (t < 256) {
      const int k0 = bid * 8;
      const int n = t;                 // 0..255
      const int T = n >> 4, rr = n & 15;
      const int c = k0 >> 5, qq = (k0 >> 3) & 3;
      _Float16 v8[8];
#pragma unroll
      for (int kk = 0; kk < 8; ++kk) {
        float f = (n < 255) ? Ws[(size_t)(k0 + kk) * 255 + n] : 0.f;
        v8[kk] = (_Float16)f;
      }
      *(half8*)&wt[(size_t)(T * 16 + c) * 512 + (qq * 16 + rr) * 8] = *(half8*)v8;
    }
  } else if (bid < 68) {               // value^T: 64 k-rows per block
    if (t < 256) {
      const int k0 = (bid - 64) * 64;
#pragma unroll
      for (int j = 0; j < 16; ++j) {
        int e = t + j * 256;           // 0..4095
        int k = k0 + (e >> 6), n = e & 63;
        float f = value[(size_t)k * O + n];
        int T = n >> 4, rr = n & 15, kc = k >> 5, qq = (k >> 3) & 3, jj = k & 7;
        vt[(size_t)(T * 8 + kc) * 512 + (qq * 16 + rr) * 8 + jj] = (_Float16)f;
      }
      if (bid == 64 && t == 0) *reg_out = 0.f;
    }
  }
  __threadfence();                     // make wt/vt device-visible
  cg::this_grid().sync();              // also covers xh_s block-level barrier

  // ======== phase B1: K-loop, 16 chunks of K=32, 4 MFMA each ========
  const _Float16* pb0 = wt + (size_t)(2 * w) * 16 * 512 + lane * 8;
  const _Float16* pb1 = wt + (size_t)(2 * w + 1) * 16 * 512 + lane * 8;
  const int a0off = r16 * XSTR, a1off = (16 + r16) * XSTR;

  floatx4 acc00 = {0,0,0,0}, acc01 = {0,0,0,0}, acc10 = {0,0,0,0}, acc11 = {0,0,0,0};
  half8 B0 = *(const half8*)pb0, B1 = *(const half8*)pb1;

#pragma unroll
  for (int c = 0; c < 16; ++c) {
    half8 n0, n1;
    if (c < 15) {
      n0 = *(const half8*)(pb0 + (c + 1) * 512);
      n1 = *(const half8*)(pb1 + (c + 1) * 512);
    }
    half8 a0 = *(const half8*)&xh_s[a0off + c * 32 + q * 8];
    half8 a1 = *(const half8*)&xh_s[a1off + c * 32 + q * 8];
    acc00 = __builtin_amdgcn_mfma_f32_16x16x32_f16(a0, B0, acc00, 0, 0, 0);
    acc01 = __builtin_amdgcn_mfma_f32_16x16x32_f16(a0, B1, acc01, 0, 0, 0);
    acc10 = __builtin_amdgcn_mfma_f32_16x16x32_f16(a1, B0, acc10, 0, 0, 0);
    acc11 = __builtin_amdgcn_mfma_f32_16x16x32_f16(a1, B1, acc11, 0, 0, 0);
    if (c < 15) { B0 = n0; B1 = n1; }
  }

  // ---- fused epilogue: bias + sigmoid + reg on registers (pre-barrier) ----
  const int c0 = w * 32 + r16, c1 = c0 + 16;   // c0 <= 239; c1 <= 255
  float pv00[4], pv01[4], pv10[4], pv11[4];
  float s0 = 0.f, s1 = 0.f;
  {
    const float b0 = bs[c0];
    const float b1 = (c1 < 255) ? bs[c1] : 0.f;
#pragma unroll
    for (int r = 0; r < 4; ++r) {
      float p;
      p = 1.f / (1.f + __expf(-(acc00[r] + b0))); pv00[r] = p;
      s0 += __logf(fmaxf(p * (1.f - p), 1e-5f));
      p = 1.f / (1.f + __expf(-(acc10[r] + b0))); pv10[r] = p;
      s0 += __logf(fmaxf(p * (1.f - p), 1e-5f));
      p = 1.f / (1.f + __expf(-(acc01[r] + b1))); pv01[r] = p;
      s1 += __logf(fmaxf(p * (1.f - p), 1e-5f));
      p = 1.f / (1.f + __expf(-(acc11[r] + b1))); pv11[r] = p;
      s1 += __logf(fmaxf(p * (1.f - p), 1e-5f));
    }
  }
  float rsum;
  {
    const int d0 = 31 - __clz(c0 + 1);
    rsum = s0 * (-0.5f / (8192.0f * (float)(1 << d0)));
    if (c1 < 255) {
      const int d1 = 31 - __clz(c1 + 1);
      rsum += s1 * (-0.5f / (8192.0f * (float)(1 << d1)));
    }
  }
#pragma unroll
  for (int off = 32; off; off >>= 1) rsum += __shfl_down(rsum, off, 64);

  __syncthreads();   // all xh_s reads done before L_s overlays it

  {
#pragma unroll
    for (int r = 0; r < 4; ++r) {
      const int row0 = q * 4 + r, row1 = row0 + 16;
      L_s[row0 * LSTR + c0] = pv00[r];
      L_s[row0 * LSTR + c1] = pv01[r];   // col 255 in-bounds, never read
      L_s[row1 * LSTR + c0] = pv10[r];
      L_s[row1 * LSTR + c1] = pv11[r];
    }
    if (lane == 0) red_s[w] = rsum;
  }
  __syncthreads();   // probabilities visible to all waves

  if (t == 0) {
    float s = 0.f;
#pragma unroll
    for (int i = 0; i < 8; ++i) s += red_s[i];
    atomicAdd(reg_out, s);
  }

  // ---- prefetch vt B-frags for phase B3 (latency hides under B2) ----
  half8 VB[8];
  {
    const int tn = w >> 1;
    const _Float16* vb = vt + (size_t)(tn * 8) * 512 + lane * 8;
#pragma unroll
    for (int kc = 0; kc < 8; ++kc) VB[kc] = *(const half8*)(vb + kc * 512);
  }

  // ======== phase B2: path products, 8 leaves x 2 rows per thread ========
  {
    const int g8 = t & 31, rp = t >> 5;
    const int Lb = g8 * 8;
#pragma unroll
    for (int rr = 0; rr < 2; ++rr) {
      const int row = rp * 2 + rr;
      const float* Lr = &L_s[row * LSTR];
      float pre = 1.f;
#pragma unroll
      for (int dd = 0; dd < 5; ++dd) {
        float p = Lr[(1 << dd) - 1 + (Lb >> (8 - dd))];
        float br = ((Lb >> (7 - dd)) & 1) ? (1.f - p) : p;
        pre *= fmaxf(br, 1e-5f);
      }
      float p5 = Lr[31 + g8];
      float s5a = fmaxf(p5, 1e-5f), s5b = fmaxf(1.f - p5, 1e-5f);
      float p6a = Lr[63 + 2 * g8], p6b = Lr[63 + 2 * g8 + 1];
      float p7v[4];
#pragma unroll
      for (int m = 0; m < 4; ++m) p7v[m] = Lr[127 + 4 * g8 + m];
      _Float16 ph[8];
#pragma unroll
      for (int j = 0; j < 8; ++j) {
        float s5 = (j & 4) ? s5b : s5a;
        float p6 = (j & 4) ? p6b : p6a;
        float s6 = fmaxf((j & 2) ? (1.f - p6) : p6, 1e-5f);
        float p7 = p7v[j >> 1];
        float s7 = fmaxf((j & 1) ? (1.f - p7) : p7, 1e-5f);
        ph[j] = (_Float16)(pre * s5 * s6 * s7);
      }
      *(half8*)&P_h[row * PSTR + Lb] = *(half8*)ph;
    }
  }
  __syncthreads();   // P_h ready

  // ======== phase B3: out[32][64] = P @ value via fp16 MFMA ========
  {
    const int tm = w & 1, tn = w >> 1;       // 2 m-tiles x 4 n-tiles of 16
    floatx4 C = {0, 0, 0, 0};
    const _Float16* pa = &P_h[(tm * 16 + r16) * PSTR + q * 8];
#pragma unroll
    for (int kc = 0; kc < 8; ++kc) {
      half8 A8 = *(const half8*)(pa + kc * 32);
      C = __builtin_amdgcn_mfma_f32_16x16x32_f16(A8, VB[kc], C, 0, 0, 0);
    }
    const int col = tn * 16 + r16;
#pragma unroll
    for (int r = 0; r < 4; ++r) {
      int row = tm * 16 + q * 4 + r;
      out[(size_t)(R0 + row) * O + col] = C[r];
    }
  }
}

extern "C" void kernel_launch(void* const* d_in, const int* in_sizes, int n_in,
                              void* d_out, int out_size, void* d_ws, size_t ws_size,
                              hipStream_t stream) {
  const float* x     = (const float*)d_in[0];
  const float* Ws    = (const float*)d_in[1];
  const float* bs    = (const float*)d_in[2];
  const float* value = (const float*)d_in[3];
  float* outp = (float*)d_out;
  float* reg_slot = outp + (size_t)8192 * O;          // index 524288
  _Float16* wt = (_Float16*)d_ws;                     // frag-major W^T fp16, 256 KB
  _Float16* vt = wt + 256 * 512;                      // frag-major value^T fp16, 32 KB

  void* args[] = { (void*)&x, (void*)&Ws, (void*)&bs, (void*)&value,
                   (void*)&wt, (void*)&vt, (void*)&outp, (void*)&reg_slot };
  hipLaunchCooperativeKernel((void*)sdt_fused, dim3(256), dim3(512),
                             args, 0, stream);
}

// Round 3
// 82.480 us; speedup vs baseline: 1.9510x; 1.9510x over previous
//
#include <hip/hip_runtime.h>

// SDT forward, fp16 MFMA (fp32 accumulate), v4: v1 two-dispatch skeleton +
// deep B-prefetch (12 chunks pre-barrier, depth-3 groups) + register-fused
// sigmoid/bias/reg epilogue (from v3, numerics verified) + vt reg prefetch.
// Lesson from v3: cooperative grid.sync costs ~tens of us on gfx950 -- never
// use it for fine-grained dependencies; two dispatches are cheaper.
// Layouts (HW-verified): A/B^T lane&15->row, (lane>>4)*8->k;
// C/D: col=lane&15, row=(lane>>4)*4+reg.

typedef __attribute__((ext_vector_type(8))) _Float16 half8;
typedef __attribute__((ext_vector_type(4))) _Float16 half4;
typedef __attribute__((ext_vector_type(4))) float floatx4;

constexpr int O = 64;
constexpr int XSTR = 520;   // x-tile LDS row stride (halfs): 1040 B
constexpr int PSTR = 280;   // P_h row stride (halfs): 560 B (16B-aligned)
constexpr int LSTR = 260;   // L_s row stride (floats)

// ---- pre: W^T fp16 frag-major; value^T fp16 frag-major; zero reg ----
// wt layout: block (T*16+c) of 1024 B; lane=(q*16+r16); elem j:
//   wt[(T*16+c)*512 + lane*8 + j] = W[k= c*32+q*8+j][n= T*16+r16]
__global__ __launch_bounds__(256) void sdt_pre(
    const float* __restrict__ Ws, const float* __restrict__ value,
    _Float16* __restrict__ wt, _Float16* __restrict__ vt,
    float* __restrict__ reg_slot)
{
  const int bid = blockIdx.x, t = threadIdx.x;
  if (bid < 64) {                      // W: 8 k-rows per block, coalesced reads
    const int k0 = bid * 8;
    const int n = t;                   // 0..255
    const int T = n >> 4, r = n & 15;
    const int c = k0 >> 5, q = (k0 >> 3) & 3;
    _Float16 v8[8];
#pragma unroll
    for (int kk = 0; kk < 8; ++kk) {
      float f = (n < 255) ? Ws[(size_t)(k0 + kk) * 255 + n] : 0.f;
      v8[kk] = (_Float16)f;
    }
    *(half8*)&wt[(size_t)(T * 16 + c) * 512 + (q * 16 + r) * 8] = *(half8*)v8;
  } else {                             // value^T: 64 k-rows per block
    const int k0 = (bid - 64) * 64;
#pragma unroll
    for (int j = 0; j < 16; ++j) {
      int e = t + j * 256;             // 0..4095
      int k = k0 + (e >> 6), n = e & 63;
      float f = value[(size_t)k * O + n];
      int T = n >> 4, r = n & 15, kc = k >> 5, q = (k >> 3) & 3, jj = k & 7;
      vt[(size_t)(T * 8 + kc) * 512 + (q * 16 + r) * 8 + jj] = (_Float16)f;
    }
    if (bid == 64 && t == 0) *reg_slot = 0.f;
  }
}

__global__ __launch_bounds__(512, 1) void sdt_main(
    const float* __restrict__ x, const _Float16* __restrict__ wt,
    const _Float16* __restrict__ vt, const float* __restrict__ bs,
    float* __restrict__ out, float* __restrict__ reg_out)
{
  // Overlay: phase 1 x-tile fp16 (33280 B) / phase 2 L_s + P_h.
  __shared__ __align__(16) char smem[33280 + 17920];
  _Float16* xh_s = (_Float16*)smem;              // [32][520]
  float*    L_s  = (float*)smem;                 // [32][260]
  _Float16* P_h  = (_Float16*)(smem + 33280);    // [32][280]
  __shared__ float red_s[8];

  const int t = threadIdx.x, lane = t & 63, w = t >> 6;   // 8 waves
  const int q = lane >> 4, r16 = lane & 15;
  const int R0 = blockIdx.x * 32;

  // ---- issue B loads for chunks 0..11 (3 groups of 4) before staging ----
  // Latency hides under x-staging + barrier.
  const _Float16* pb0 = wt + (size_t)(2 * w) * 16 * 512 + lane * 8;
  const _Float16* pb1 = wt + (size_t)(2 * w + 1) * 16 * 512 + lane * 8;
  half8 Bs0[3][4], Bs1[3][4];          // [slot][chunk-in-group]
#pragma unroll
  for (int s = 0; s < 3; ++s)
#pragma unroll
    for (int j = 0; j < 4; ++j) {
      Bs0[s][j] = *(const half8*)(pb0 + (s * 4 + j) * 512);
      Bs1[s][j] = *(const half8*)(pb1 + (s * 4 + j) * 512);
    }

  // ---- stage + convert x tile once (coalesced) ----
  {
    const int row = t >> 4, l4 = (t & 15) * 4;
    const float* xrow = x + (size_t)(R0 + row) * 512;
#pragma unroll
    for (int i = 0; i < 8; ++i) {
      const int k = l4 + i * 64;
      float4 v = *(const float4*)(xrow + k);
      half4 h = {(_Float16)v.x, (_Float16)v.y, (_Float16)v.z, (_Float16)v.w};
      *(half4*)&xh_s[row * XSTR + k] = h;
    }
  }
  __syncthreads();   // barrier 1: x tile staged

  // ---- K-loop: 4 groups of 4 chunks (K=32 each), 4 MFMA per chunk ----
  floatx4 acc00 = {0,0,0,0}, acc01 = {0,0,0,0}, acc10 = {0,0,0,0}, acc11 = {0,0,0,0};
  const int a0off = r16 * XSTR + q * 8, a1off = (16 + r16) * XSTR + q * 8;

#pragma unroll
  for (int g = 0; g < 4; ++g) {
    const int s = g % 3;
#pragma unroll
    for (int j = 0; j < 4; ++j) {
      const int c = g * 4 + j;
      half8 a0 = *(const half8*)&xh_s[a0off + c * 32];
      half8 a1 = *(const half8*)&xh_s[a1off + c * 32];
      half8 b0 = Bs0[s][j], b1 = Bs1[s][j];
      acc00 = __builtin_amdgcn_mfma_f32_16x16x32_f16(a0, b0, acc00, 0, 0, 0);
      acc01 = __builtin_amdgcn_mfma_f32_16x16x32_f16(a0, b1, acc01, 0, 0, 0);
      acc10 = __builtin_amdgcn_mfma_f32_16x16x32_f16(a1, b0, acc10, 0, 0, 0);
      acc11 = __builtin_amdgcn_mfma_f32_16x16x32_f16(a1, b1, acc11, 0, 0, 0);
    }
    if (g == 0) {                      // refill slot 0 with group 3 (512cy cover)
#pragma unroll
      for (int j = 0; j < 4; ++j) {
        Bs0[0][j] = *(const half8*)(pb0 + (12 + j) * 512);
        Bs1[0][j] = *(const half8*)(pb1 + (12 + j) * 512);
      }
    }
  }

  // ---- fused epilogue: bias + sigmoid + reg on registers (pre-barrier) ----
  const int c0 = w * 32 + r16, c1 = c0 + 16;   // c0 <= 239; c1 <= 255
  float pv00[4], pv01[4], pv10[4], pv11[4];
  float s0 = 0.f, s1 = 0.f;
  {
    const float b0 = bs[c0];
    const float b1 = (c1 < 255) ? bs[c1] : 0.f;
#pragma unroll
    for (int r = 0; r < 4; ++r) {
      float p;
      p = 1.f / (1.f + __expf(-(acc00[r] + b0))); pv00[r] = p;
      s0 += __logf(fmaxf(p * (1.f - p), 1e-5f));
      p = 1.f / (1.f + __expf(-(acc10[r] + b0))); pv10[r] = p;
      s0 += __logf(fmaxf(p * (1.f - p), 1e-5f));
      p = 1.f / (1.f + __expf(-(acc01[r] + b1))); pv01[r] = p;
      s1 += __logf(fmaxf(p * (1.f - p), 1e-5f));
      p = 1.f / (1.f + __expf(-(acc11[r] + b1))); pv11[r] = p;
      s1 += __logf(fmaxf(p * (1.f - p), 1e-5f));
    }
  }
  float rsum;
  {
    const int d0 = 31 - __clz(c0 + 1);
    rsum = s0 * (-0.5f / (8192.0f * (float)(1 << d0)));
    if (c1 < 255) {
      const int d1 = 31 - __clz(c1 + 1);
      rsum += s1 * (-0.5f / (8192.0f * (float)(1 << d1)));
    }
  }
#pragma unroll
  for (int off = 32; off; off >>= 1) rsum += __shfl_down(rsum, off, 64);

  __syncthreads();   // barrier 2: all xh_s reads done before L_s overlays it

  {
#pragma unroll
    for (int r = 0; r < 4; ++r) {
      const int row0 = q * 4 + r, row1 = row0 + 16;
      L_s[row0 * LSTR + c0] = pv00[r];
      L_s[row0 * LSTR + c1] = pv01[r];   // col 255 in-bounds, never read
      L_s[row1 * LSTR + c0] = pv10[r];
      L_s[row1 * LSTR + c1] = pv11[r];
    }
    if (lane == 0) red_s[w] = rsum;
  }
  __syncthreads();   // barrier 3: probabilities visible to all waves

  if (t == 0) {
    float s = 0.f;
#pragma unroll
    for (int i = 0; i < 8; ++i) s += red_s[i];
    atomicAdd(reg_out, s);
  }

  // ---- prefetch vt B-frags for phase 2c (latency hides under 2b) ----
  half8 VB[8];
  {
    const int tn = w >> 1;
    const _Float16* vb = vt + (size_t)(tn * 8) * 512 + lane * 8;
#pragma unroll
    for (int kc = 0; kc < 8; ++kc) VB[kc] = *(const half8*)(vb + kc * 512);
  }

  // ---- phase 2b: path products, 8 leaves x 2 rows per thread ----
  {
    const int g8 = t & 31, rp = t >> 5;
    const int Lb = g8 * 8;
#pragma unroll
    for (int rr = 0; rr < 2; ++rr) {
      const int row = rp * 2 + rr;
      const float* Lr = &L_s[row * LSTR];
      float pre = 1.f;
#pragma unroll
      for (int dd = 0; dd < 5; ++dd) {
        float p = Lr[(1 << dd) - 1 + (Lb >> (8 - dd))];
        float br = ((Lb >> (7 - dd)) & 1) ? (1.f - p) : p;
        pre *= fmaxf(br, 1e-5f);
      }
      float p5 = Lr[31 + g8];
      float s5a = fmaxf(p5, 1e-5f), s5b = fmaxf(1.f - p5, 1e-5f);
      float p6a = Lr[63 + 2 * g8], p6b = Lr[63 + 2 * g8 + 1];
      float p7v[4];
#pragma unroll
      for (int m = 0; m < 4; ++m) p7v[m] = Lr[127 + 4 * g8 + m];
      _Float16 ph[8];
#pragma unroll
      for (int j = 0; j < 8; ++j) {
        float s5 = (j & 4) ? s5b : s5a;
        float p6 = (j & 4) ? p6b : p6a;
        float s6 = fmaxf((j & 2) ? (1.f - p6) : p6, 1e-5f);
        float p7 = p7v[j >> 1];
        float s7 = fmaxf((j & 1) ? (1.f - p7) : p7, 1e-5f);
        ph[j] = (_Float16)(pre * s5 * s6 * s7);
      }
      *(half8*)&P_h[row * PSTR + Lb] = *(half8*)ph;
    }
  }
  __syncthreads();   // barrier 4: P_h ready

  // ---- phase 2c: out[32][64] = P @ value via fp16 MFMA ----
  {
    const int tm = w & 1, tn = w >> 1;       // 2 m-tiles x 4 n-tiles of 16
    floatx4 C = {0, 0, 0, 0};
    const _Float16* pa = &P_h[(tm * 16 + r16) * PSTR + q * 8];
#pragma unroll
    for (int kc = 0; kc < 8; ++kc) {
      half8 A8 = *(const half8*)(pa + kc * 32);
      C = __builtin_amdgcn_mfma_f32_16x16x32_f16(A8, VB[kc], C, 0, 0, 0);
    }
    const int col = tn * 16 + r16;
#pragma unroll
    for (int r = 0; r < 4; ++r) {
      int row = tm * 16 + q * 4 + r;
      out[(size_t)(R0 + row) * O + col] = C[r];
    }
  }
}

extern "C" void kernel_launch(void* const* d_in, const int* in_sizes, int n_in,
                              void* d_out, int out_size, void* d_ws, size_t ws_size,
                              hipStream_t stream) {
  const float* x     = (const float*)d_in[0];
  const float* Ws    = (const float*)d_in[1];
  const float* bs    = (const float*)d_in[2];
  const float* value = (const float*)d_in[3];
  float* outp = (float*)d_out;
  float* reg_slot = outp + (size_t)8192 * O;          // index 524288
  _Float16* wt = (_Float16*)d_ws;                     // frag-major W^T fp16, 256 KB
  _Float16* vt = wt + 256 * 512;                      // frag-major value^T fp16, 32 KB

  sdt_pre<<<68, 256, 0, stream>>>(Ws, value, wt, vt, reg_slot);
  sdt_main<<<256, 512, 0, stream>>>(x, wt, vt, bs, outp, reg_slot);
}